// Round 4
// baseline (2782.507 us; speedup 1.0000x reference)
//
#include <hip/hip_runtime.h>
#include <math.h>

// Problem constants
constexpr int B_ = 4096;
constexpr int T_ = 20;
constexpr int XD = 256;   // X_DIM
constexpr int ZD = 128;   // Z_DIM
constexpr int HD = 512;   // H_DIM
constexpr int DD = 384;   // X+Z

using short8 = __attribute__((ext_vector_type(8))) short;
using bf16x8 = __attribute__((ext_vector_type(8))) __bf16;
using f32x4  = __attribute__((ext_vector_type(4))) float;

__device__ __forceinline__ float lrelu_f(float v) { return v > 0.f ? v : 0.2f * v; }
__device__ __forceinline__ float softplus_f(float v) {
    return log1pf(expf(-fabsf(v))) + fmaxf(v, 0.f);
}
__device__ __forceinline__ float sigmoid_f(float v) { return 1.f / (1.f + expf(-v)); }

// float -> bf16 (round to nearest even), finite inputs
__device__ __forceinline__ unsigned short f2b(float f) {
    unsigned u = __builtin_bit_cast(unsigned, f);
    u += 0x7fff + ((u >> 16) & 1);
    return (unsigned short)(u >> 16);
}

__device__ __forceinline__ f32x4 mfma16(short8 a, short8 b, f32x4 c) {
    return __builtin_amdgcn_mfma_f32_16x16x32_bf16(
        __builtin_bit_cast(bf16x8, a), __builtin_bit_cast(bf16x8, b), c, 0, 0, 0);
}

// async global->LDS, 16 B per lane; lds base must be wave-uniform
__device__ __forceinline__ void load_lds16(const unsigned short* g, unsigned short* l) {
    __builtin_amdgcn_global_load_lds(
        (const __attribute__((address_space(1))) unsigned int*)g,
        (__attribute__((address_space(3))) unsigned int*)l,
        16, 0, 0);
}

// ---------------------------------------------------------------------------
// 128x128-tile bf16 MFMA GEMM core, 2-phase prefetch (T3-minimum):
//   C[128,128] += A1[128,K1] @ W1[128,K1]^T + A2[128,K2] @ W2[128,K2]^T
// BK=32, double-buffered LDS (As/Bs each hold 2 x 128x32 bf16 = 16 KB).
// Staged via global_load_lds(16B) with chunk swizzle c' = c ^ ((row>>1)&3)
// applied on the GLOBAL source and on the ds_read side (rule #21).
// Per iteration: stage(i+1 -> buf^1) || ds_read+MFMA(buf) ; one barrier.
// K1,K2 multiples of 32 (K2 may be 0); lda/ldw multiples of 8.
// acc[mi][ni][r]: row = bm + wr*64 + mi*16 + (lane>>4)*4 + r,
//                 col = bn + wc*64 + ni*16 + (lane&15)
// ---------------------------------------------------------------------------
__device__ __forceinline__ void gemm_core(
    const unsigned short* A1, int lda1, int K1,
    const unsigned short* A2, int lda2, int K2,
    const unsigned short* W1, int ldw1,
    const unsigned short* W2, int ldw2,
    int bm, int bn,
    unsigned short* As, unsigned short* Bs,   // each 8192 shorts (2 buffers)
    f32x4 (&acc)[4][4])
{
    const int tid  = threadIdx.x;
    const int lane = tid & 63;
    const int wave = tid >> 6;
    const int wr = wave >> 1, wc = wave & 1;
    const int fr = lane & 15, fg = lane >> 4;
    const int cswz = fg ^ ((fr >> 1) & 3);      // read-side chunk swizzle

    // staging: 512 chunks (16 B) per operand per K-tile, 2 rounds of 256
    const int j0 = tid;
    const int j1 = 256 + tid;
    const int r0 = j0 >> 2, c0 = (j0 & 3) ^ ((r0 >> 1) & 3);
    const int r1 = j1 >> 2, c1 = (j1 & 3) ^ ((r1 >> 1) & 3);

    const int n1 = K1 / 32;
    const int nt = n1 + K2 / 32;

    auto stage = [&](int i, int buf) {
        const unsigned short* Ag;
        const unsigned short* Wg;
        int lda, ldw, kb;
        if (i < n1) { Ag = A1; Wg = W1; lda = lda1; ldw = ldw1; kb = i * 32; }
        else        { Ag = A2; Wg = W2; lda = lda2; ldw = ldw2; kb = (i - n1) * 32; }
        unsigned short* lA = As + buf * 4096 + wave * 512;   // wave-uniform bases
        unsigned short* lB = Bs + buf * 4096 + wave * 512;
        load_lds16(Ag + (size_t)(bm + r0) * lda + kb + c0 * 8, lA);
        load_lds16(Ag + (size_t)(bm + r1) * lda + kb + c1 * 8, lA + 2048);
        load_lds16(Wg + (size_t)(bn + r0) * ldw + kb + c0 * 8, lB);
        load_lds16(Wg + (size_t)(bn + r1) * ldw + kb + c1 * 8, lB + 2048);
    };

    auto compute = [&](int buf) {
        const unsigned short* Ab_ = As + buf * 4096;
        const unsigned short* Bb_ = Bs + buf * 4096;
        short8 af[4], bv[4];
#pragma unroll
        for (int mi = 0; mi < 4; ++mi)
            af[mi] = *reinterpret_cast<const short8*>(Ab_ + (wr * 64 + mi * 16 + fr) * 32 + cswz * 8);
#pragma unroll
        for (int ni = 0; ni < 4; ++ni)
            bv[ni] = *reinterpret_cast<const short8*>(Bb_ + (wc * 64 + ni * 16 + fr) * 32 + cswz * 8);
#pragma unroll
        for (int mi = 0; mi < 4; ++mi)
#pragma unroll
            for (int ni = 0; ni < 4; ++ni)
                acc[mi][ni] = mfma16(af[mi], bv[ni], acc[mi][ni]);
    };

    stage(0, 0);
    __syncthreads();            // full drain (vmcnt 0 + lgkm 0) + barrier
    int cur = 0;
    for (int i = 1; i < nt; ++i) {
        stage(i, cur ^ 1);      // next tile's loads fly under this tile's MFMA
        compute(cur);
        __syncthreads();        // drains stage; all waves done reading buf cur
        cur ^= 1;
    }
    compute(cur);
}

// GEMM + bias + activation -> bf16 output. ACT: 0 none, 1 lrelu, 2 softplus(lrelu)
template <int ACT>
__global__ __launch_bounds__(256) void k_gemm_act(
    const unsigned short* __restrict__ A1, int lda1, int K1,
    const unsigned short* __restrict__ A2, int lda2, int K2,
    const unsigned short* __restrict__ W1, int ldw1,
    const unsigned short* __restrict__ W2, int ldw2,
    const float* __restrict__ bias,
    unsigned short* __restrict__ DB, int lddb)
{
    __shared__ unsigned short As[8192];
    __shared__ unsigned short Bs[8192];
    const int bm = blockIdx.y * 128, bn = blockIdx.x * 128;
    f32x4 acc[4][4] = {};
    gemm_core(A1, lda1, K1, A2, lda2, K2, W1, ldw1, W2, ldw2, bm, bn, As, Bs, acc);

    const int tid = threadIdx.x, lane = tid & 63, wave = tid >> 6;
    const int wr = wave >> 1, wc = wave & 1, fr = lane & 15, rg = lane >> 4;
    float bb[4];
#pragma unroll
    for (int ni = 0; ni < 4; ++ni)
        bb[ni] = bias ? bias[bn + wc * 64 + ni * 16 + fr] : 0.f;
#pragma unroll
    for (int mi = 0; mi < 4; ++mi)
#pragma unroll
        for (int r = 0; r < 4; ++r) {
            const int row = bm + wr * 64 + mi * 16 + rg * 4 + r;
#pragma unroll
            for (int ni = 0; ni < 4; ++ni) {
                float v = acc[mi][ni][r] + bb[ni];
                if (ACT == 1) v = lrelu_f(v);
                else if (ACT == 2) v = softplus_f(lrelu_f(v));
                DB[(size_t)row * lddb + (bn + wc * 64 + ni * 16 + fr)] = f2b(v);
            }
        }
}

// mean/logvar fused via block-diagonal weight [256 x 1024]:
// cols 0-127 = mean (lrelu) -> out_z, out_mean (f32) + meanb (bf16)
// cols 128-255 = logvar (lrelu) -> out_lv (f32)
__global__ __launch_bounds__(256) void k_meanlv(
    const unsigned short* __restrict__ A,
    const unsigned short* __restrict__ W,
    const float* __restrict__ bias,
    float* __restrict__ oz, float* __restrict__ om, float* __restrict__ olv,
    unsigned short* __restrict__ meanb)
{
    __shared__ unsigned short As[8192];
    __shared__ unsigned short Bs[8192];
    const int bm = blockIdx.y * 128, bn = blockIdx.x * 128;   // bn in {0,128}
    f32x4 acc[4][4] = {};
    gemm_core(A, 1024, 1024, A, 1024, 0, W, 1024, W, 1024, bm, bn, As, Bs, acc);

    const int tid = threadIdx.x, lane = tid & 63, wave = tid >> 6;
    const int wr = wave >> 1, wc = wave & 1, fr = lane & 15, rg = lane >> 4;
    float bb[4];
#pragma unroll
    for (int ni = 0; ni < 4; ++ni)
        bb[ni] = bias[bn + wc * 64 + ni * 16 + fr];
#pragma unroll
    for (int mi = 0; mi < 4; ++mi)
#pragma unroll
        for (int r = 0; r < 4; ++r) {
            const int row = bm + wr * 64 + mi * 16 + rg * 4 + r;
#pragma unroll
            for (int ni = 0; ni < 4; ++ni) {
                const int col = bn + wc * 64 + ni * 16 + fr;
                float v = lrelu_f(acc[mi][ni][r] + bb[ni]);
                if (bn == 0) {  // mean half
                    const size_t o = (size_t)row * (T_ * ZD) + col;
                    oz[o] = v; om[o] = v;
                    meanb[(size_t)row * ZD + col] = f2b(v);
                } else {        // logvar half
                    olv[(size_t)row * (T_ * ZD) + (col - 128)] = v;
                }
            }
        }
}

// gates GEMM with gate-interleaved weight rows + fused LSTM pointwise.
// Reordered col c <-> (group=c>>6, gate=(c>>4)&3, nn=c&15), unit n=group*16+nn.
// h fp32 buffer eliminated: hn written to ohl[t] and oh[t+1] (out_hout[t]==out_hlo[t-1]).
__global__ __launch_bounds__(256) void k_gates_lstm(
    const unsigned short* __restrict__ phib,
    const unsigned short* __restrict__ hbin,
    const unsigned short* __restrict__ Wih,   // [2048][1024] reordered rows
    const unsigned short* __restrict__ Whh,   // [2048][512] reordered rows
    const float* __restrict__ br,             // reordered b_ih+b_hh
    float* __restrict__ c,
    unsigned short* __restrict__ hbout,
    float* __restrict__ ohl,                  // out_hlo + t*HD
    float* __restrict__ oh_next)              // out_hout + (t+1)*HD, or null
{
    __shared__ unsigned short As[8192];
    __shared__ unsigned short Bs[8192];
    const int bm = blockIdx.y * 128, bn = blockIdx.x * 128;
    f32x4 acc[4][4] = {};
    gemm_core(phib, 1024, 1024, hbin, 512, 512, Wih, 1024, Whh, 512, bm, bn, As, Bs, acc);

    const int tid = threadIdx.x, lane = tid & 63, wave = tid >> 6;
    const int wr = wave >> 1, wc = wave & 1, fr = lane & 15, rg = lane >> 4;
    const int n = ((bn + wc * 64) >> 6) * 16 + fr;     // hidden unit index
    float bb[4];
#pragma unroll
    for (int ni = 0; ni < 4; ++ni)
        bb[ni] = br[bn + wc * 64 + ni * 16 + fr];
#pragma unroll
    for (int mi = 0; mi < 4; ++mi)
#pragma unroll
        for (int r = 0; r < 4; ++r) {
            const int row = bm + wr * 64 + mi * 16 + rg * 4 + r;
            const size_t idx = (size_t)row * HD + n;
            const float gi = acc[mi][0][r] + bb[0];
            const float gf = acc[mi][1][r] + bb[1];
            const float gg = acc[mi][2][r] + bb[2];
            const float go = acc[mi][3][r] + bb[3];
            const float co = c[idx];
            const float cn = sigmoid_f(gf) * co + sigmoid_f(gi) * tanhf(gg);
            const float hn = sigmoid_f(go) * tanhf(cn);
            c[idx] = cn;
            hbout[idx] = f2b(hn);
            const size_t ob = (size_t)row * (T_ * HD) + n;
            ohl[ob] = hn;                       // h after update
            if (oh_next) oh_next[ob] = hn;      // == h BEFORE update at t+1
        }
}

// ---------------------------------------------------------------------------
// init: c = 0, hb0 = 0, out_hout[:, 0, :] = 0 (d_out is poisoned by harness)
__global__ __launch_bounds__(256) void init_state(
    float* __restrict__ c, unsigned short* __restrict__ hb,
    float* __restrict__ oh0)
{
    const int i = blockIdx.x * 256 + threadIdx.x;   // B_*HD
    c[i] = 0.f; hb[i] = 0;
    const int b = i >> 9, nn = i & 511;
    oh0[(size_t)b * (T_ * HD) + nn] = 0.f;
}

__global__ __launch_bounds__(256) void f32_to_bf16(
    const float* __restrict__ src, unsigned short* __restrict__ dst, int n4)
{
    const int i = blockIdx.x * 256 + threadIdx.x;
    if (i >= n4) return;
    float4 v = reinterpret_cast<const float4*>(src)[i];
    ushort4 o;
    o.x = f2b(v.x); o.y = f2b(v.y); o.z = f2b(v.z); o.w = f2b(v.w);
    reinterpret_cast<ushort4*>(dst)[i] = o;
}

// x[:, t, :] (fp32, row stride T*XD) -> xb [B][XD] bf16
__global__ __launch_bounds__(256) void conv_xt(
    const float* __restrict__ x, int t, unsigned short* __restrict__ xb)
{
    const int i = blockIdx.x * 256 + threadIdx.x;   // B_*XD/4
    const int b = i >> 6;
    const int d = i & 63;
    float4 v = reinterpret_cast<const float4*>(x + (size_t)b * (T_ * XD) + (size_t)t * XD)[d];
    ushort4 o;
    o.x = f2b(v.x); o.y = f2b(v.y); o.z = f2b(v.z); o.w = f2b(v.w);
    reinterpret_cast<ushort4*>(xb)[i] = o;
}

// Wub[1024][768] = [Wm1; Wv1] (bf16)
__global__ __launch_bounds__(256) void prep_wu(
    const float* __restrict__ Wm1, const float* __restrict__ Wv1,
    unsigned short* __restrict__ Wub)
{
    const int k = blockIdx.x * 256 + threadIdx.x;   // 0..767
    const int nrow = blockIdx.y;                    // 0..1023
    const float v = nrow < 512 ? Wm1[nrow * 768 + k] : Wv1[(nrow - 512) * 768 + k];
    Wub[nrow * 768 + k] = f2b(v);
}

// Wmlv[256][1024] block-diagonal: [Wm2 0; 0 Wv2] (bf16)
__global__ __launch_bounds__(256) void prep_wmlv(
    const float* __restrict__ Wm2, const float* __restrict__ Wv2,
    unsigned short* __restrict__ Wmlv)
{
    const int k = blockIdx.x * 256 + threadIdx.x;   // 0..1023
    const int cc = blockIdx.y;                      // 0..255
    float v = 0.f;
    if (cc < 128) { if (k < 512) v = Wm2[cc * 512 + k]; }
    else          { if (k >= 512) v = Wv2[(cc - 128) * 512 + (k - 512)]; }
    Wmlv[cc * 1024 + k] = f2b(v);
}

// gate-interleaved reorder of W_ih, W_hh
__global__ __launch_bounds__(256) void prep_wg(
    const float* __restrict__ Wih, const float* __restrict__ Whh,
    unsigned short* __restrict__ Wrih, unsigned short* __restrict__ Wrhh)
{
    const int cc = blockIdx.y;                      // 0..2047
    const int gate = (cc >> 4) & 3;
    const int n = ((cc >> 6) << 4) + (cc & 15);
    const int orig = gate * 512 + n;
    const int kk = blockIdx.x * 256 + threadIdx.x;  // 0..1535
    if (kk < 1024) Wrih[(size_t)cc * 1024 + kk] = f2b(Wih[(size_t)orig * 1024 + kk]);
    else           Wrhh[(size_t)cc * 512 + (kk - 1024)] = f2b(Whh[(size_t)orig * 512 + (kk - 1024)]);
}

// At[k][j] = bf16(A[j][k])  (A is [384][384] fp32 row-major)
__global__ __launch_bounds__(256) void prep_at(
    const float* __restrict__ A, unsigned short* __restrict__ At)
{
    const int i = blockIdx.x * 256 + threadIdx.x;   // 384*384
    const int k = i / DD, j = i % DD;
    At[(size_t)k * DD + j] = f2b(A[(size_t)j * DD + k]);
}

__global__ __launch_bounds__(256) void prep_bias(
    const float* __restrict__ bm1, const float* __restrict__ bv1,
    const float* __restrict__ bm2, const float* __restrict__ bv2,
    const float* __restrict__ bih, const float* __restrict__ bhh,
    float* __restrict__ bu, float* __restrict__ bmlv, float* __restrict__ br)
{
    const int i = blockIdx.x * 256 + threadIdx.x;   // 0..4095
    if (i < 1024) {
        bu[i] = i < 512 ? bm1[i] : bv1[i - 512];
    } else if (i < 1280) {
        const int j = i - 1024;
        bmlv[j] = j < 128 ? bm2[j] : bv2[j - 128];
    } else if (i >= 2048) {
        const int cb = i - 2048;
        const int gate = (cb >> 4) & 3;
        const int n = ((cb >> 6) << 4) + (cb & 15);
        const int orig = gate * 512 + n;
        br[cb] = bih[orig] + bhh[orig];
    }
}

extern "C" void kernel_launch(void* const* d_in, const int* in_sizes, int n_in,
                              void* d_out, int out_size, void* d_ws, size_t ws_size,
                              hipStream_t stream)
{
    const float* x    = (const float*)d_in[0];
    const float* A    = (const float*)d_in[3];
    const float* Wm1  = (const float*)d_in[4];
    const float* bm1  = (const float*)d_in[5];
    const float* Wm2  = (const float*)d_in[6];
    const float* bm2  = (const float*)d_in[7];
    const float* Wv1  = (const float*)d_in[8];
    const float* bv1  = (const float*)d_in[9];
    const float* Wv2  = (const float*)d_in[10];
    const float* bv2  = (const float*)d_in[11];
    const float* Wphi = (const float*)d_in[12];
    const float* bphi = (const float*)d_in[13];
    const float* W_ih = (const float*)d_in[14];
    const float* W_hh = (const float*)d_in[15];
    const float* b_ih = (const float*)d_in[16];
    const float* b_hh = (const float*)d_in[17];

    float* out = (float*)d_out;
    float* out_z    = out;
    float* out_mean = out_z + (size_t)B_ * T_ * ZD;
    float* out_lv   = out_mean + (size_t)B_ * T_ * ZD;
    float* out_hout = out_lv + (size_t)B_ * T_ * ZD;
    float* out_hlo  = out_hout + (size_t)B_ * T_ * HD;

    // ---- workspace layout (~46 MB) ----
    char* wp = (char*)d_ws;
    auto alloc_f = [&](size_t n) { float* p = (float*)wp; wp += n * sizeof(float); return p; };
    auto alloc_b = [&](size_t n) { unsigned short* p = (unsigned short*)wp; wp += n * sizeof(unsigned short); return p; };

    float* c = alloc_f((size_t)B_ * HD);
    unsigned short* hb0   = alloc_b((size_t)B_ * HD);
    unsigned short* hb1   = alloc_b((size_t)B_ * HD);
    unsigned short* xb    = alloc_b((size_t)B_ * XD);
    unsigned short* umuvb = alloc_b((size_t)B_ * 1024);
    unsigned short* meanb = alloc_b((size_t)B_ * ZD);
    unsigned short* phib  = alloc_b((size_t)B_ * 1024);

    unsigned short* Wub   = alloc_b((size_t)1024 * 768);
    unsigned short* Wmlvb = alloc_b((size_t)256 * 1024);
    unsigned short* Atb   = alloc_b((size_t)DD * DD);
    unsigned short* Wphib = alloc_b((size_t)1024 * DD);
    unsigned short* Wcb   = alloc_b((size_t)1024 * DD);
    unsigned short* Wrih  = alloc_b((size_t)2048 * 1024);
    unsigned short* Wrhh  = alloc_b((size_t)2048 * 512);

    float* bu   = alloc_f(1024);
    float* bmlv = alloc_f(256);
    float* br   = alloc_f(2048);

    const dim3 blk(256);

    // ---- prep (once per call) ----
    init_state<<<dim3(B_ * HD / 256), blk, 0, stream>>>(c, hb0, out_hout);
    prep_wu<<<dim3(3, 1024), blk, 0, stream>>>(Wm1, Wv1, Wub);
    prep_wmlv<<<dim3(4, 256), blk, 0, stream>>>(Wm2, Wv2, Wmlvb);
    prep_wg<<<dim3(6, 2048), blk, 0, stream>>>(W_ih, W_hh, Wrih, Wrhh);
    prep_bias<<<dim3(16), blk, 0, stream>>>(bm1, bv1, bm2, bv2, b_ih, b_hh, bu, bmlv, br);
    prep_at<<<dim3(DD * DD / 256), blk, 0, stream>>>(A, Atb);
    f32_to_bf16<<<dim3(1024 * DD / 4 / 256), blk, 0, stream>>>(Wphi, Wphib, 1024 * DD / 4);
    // Wc = Wphi @ A  ([1024 x 384] bf16): folds the agg GEMM into phi
    k_gemm_act<0><<<dim3(DD / 128, 1024 / 128), blk, 0, stream>>>(
        Wphib, DD, DD, Wphib, DD, 0,
        Atb, DD, Atb, DD,
        nullptr, Wcb, DD);

    for (int t = 0; t < T_; ++t) {
        unsigned short* hbt = (t & 1) ? hb1 : hb0;   // h_t  (read)
        unsigned short* hbn = (t & 1) ? hb0 : hb1;   // h_{t+1} (written by epilogue)

        conv_xt<<<dim3(B_ * XD / 4 / 256), blk, 0, stream>>>(x, t, xb);

        // [u_m | u_v] = lrelu([x_t, h] @ Wub^T + bu)   [B, 1024]
        k_gemm_act<1><<<dim3(8, 32), blk, 0, stream>>>(
            xb, XD, XD, hbt, HD, HD,
            Wub, XD + HD, Wub + XD, XD + HD,
            bu, umuvb, 1024);

        // mean -> out_z/out_mean/meanb ; logvar -> out_lv
        k_meanlv<<<dim3(2, 32), blk, 0, stream>>>(
            umuvb, Wmlvb, bmlv,
            out_z + (size_t)t * ZD, out_mean + (size_t)t * ZD,
            out_lv + (size_t)t * ZD, meanb);

        // phi = softplus(lrelu([x_t, mean] @ Wc^T + bphi))   [B, 1024]
        k_gemm_act<2><<<dim3(8, 32), blk, 0, stream>>>(
            xb, XD, XD, meanb, ZD, ZD,
            Wcb, DD, Wcb + XD, DD,
            bphi, phib, 1024);

        // gates (reordered) + fused LSTM
        k_gates_lstm<<<dim3(16, 32), blk, 0, stream>>>(
            phib, hbt, Wrih, Wrhh, br,
            c, hbn,
            out_hlo + (size_t)t * HD,
            (t + 1 < T_) ? out_hout + (size_t)(t + 1) * HD : nullptr);
    }
}

// Round 5
// 2524.752 us; speedup vs baseline: 1.1021x; 1.1021x over previous
//
#include <hip/hip_runtime.h>
#include <math.h>

// Problem constants
constexpr int B_ = 4096;
constexpr int T_ = 20;
constexpr int XD = 256;   // X_DIM
constexpr int ZD = 128;   // Z_DIM
constexpr int HD = 512;   // H_DIM
constexpr int DD = 384;   // X+Z

using short8 = __attribute__((ext_vector_type(8))) short;
using bf16x8 = __attribute__((ext_vector_type(8))) __bf16;
using f32x4  = __attribute__((ext_vector_type(4))) float;

__device__ __forceinline__ float lrelu_f(float v) { return v > 0.f ? v : 0.2f * v; }
__device__ __forceinline__ float softplus_f(float v) {
    return log1pf(expf(-fabsf(v))) + fmaxf(v, 0.f);
}
__device__ __forceinline__ float sigmoid_f(float v) { return 1.f / (1.f + expf(-v)); }

// float -> bf16 (round to nearest even), finite inputs
__device__ __forceinline__ unsigned short f2b(float f) {
    unsigned u = __builtin_bit_cast(unsigned, f);
    u += 0x7fff + ((u >> 16) & 1);
    return (unsigned short)(u >> 16);
}

__device__ __forceinline__ f32x4 mfma16(short8 a, short8 b, f32x4 c) {
    return __builtin_amdgcn_mfma_f32_16x16x32_bf16(
        __builtin_bit_cast(bf16x8, a), __builtin_bit_cast(bf16x8, b), c, 0, 0, 0);
}

// async global->LDS, 16 B per lane; lds base must be wave-uniform
__device__ __forceinline__ void load_lds16(const unsigned short* g, unsigned short* l) {
    __builtin_amdgcn_global_load_lds(
        (const __attribute__((address_space(1))) unsigned int*)g,
        (__attribute__((address_space(3))) unsigned int*)l,
        16, 0, 0);
}

// ---------------------------------------------------------------------------
// 128x128-tile bf16 MFMA GEMM core, counted-vmcnt pipeline (T3+T4):
//   C[128,128] += A1[128,K1] @ W1[128,K1]^T + A2[128,K2] @ W2[128,K2]^T
// BK=32, double-buffered LDS. Per wave per K-tile: 4 global_load_lds(16B).
// Steady state: compute(i) || loads(i+1) in flight; after compute, stage(i+2)
// into the freed buffer and wait vmcnt(4) (= tile i+1 landed, i+2 in flight).
// vmcnt never drains to 0 in the main loop. Raw s_barrier; compiler ordering
// pinned by asm memory clobbers at each wait.
// Chunk swizzle c' = c ^ ((row>>1)&3) on global source AND ds_read (rule #21).
// K1,K2 multiples of 32 (K2 may be 0), K1+K2 >= 64; lda/ldw multiples of 8.
// acc[mi][ni][r]: row = bm + wr*64 + mi*16 + (lane>>4)*4 + r,
//                 col = bn + wc*64 + ni*16 + (lane&15)
// ---------------------------------------------------------------------------
__device__ __forceinline__ void gemm_core(
    const unsigned short* A1, int lda1, int K1,
    const unsigned short* A2, int lda2, int K2,
    const unsigned short* W1, int ldw1,
    const unsigned short* W2, int ldw2,
    int bm, int bn,
    unsigned short* As, unsigned short* Bs,   // each 8192 shorts (2 buffers)
    f32x4 (&acc)[4][4])
{
    const int tid  = threadIdx.x;
    const int lane = tid & 63;
    const int wave = tid >> 6;
    const int wr = wave >> 1, wc = wave & 1;
    const int fr = lane & 15, fg = lane >> 4;
    const int cswz = fg ^ ((fr >> 1) & 3);      // read-side chunk swizzle

    // staging: 512 chunks (16 B) per operand per K-tile, 2 rounds of 256
    const int j0 = tid;
    const int j1 = 256 + tid;
    const int r0 = j0 >> 2, c0 = (j0 & 3) ^ ((r0 >> 1) & 3);
    const int r1 = j1 >> 2, c1 = (j1 & 3) ^ ((r1 >> 1) & 3);

    const int n1 = K1 / 32;
    const int nt = n1 + K2 / 32;

    auto stage = [&](int i, int buf) {
        const unsigned short* Ag;
        const unsigned short* Wg;
        int lda, ldw, kb;
        if (i < n1) { Ag = A1; Wg = W1; lda = lda1; ldw = ldw1; kb = i * 32; }
        else        { Ag = A2; Wg = W2; lda = lda2; ldw = ldw2; kb = (i - n1) * 32; }
        unsigned short* lA = As + buf * 4096 + wave * 512;   // wave-uniform bases
        unsigned short* lB = Bs + buf * 4096 + wave * 512;
        load_lds16(Ag + (size_t)(bm + r0) * lda + kb + c0 * 8, lA);
        load_lds16(Ag + (size_t)(bm + r1) * lda + kb + c1 * 8, lA + 2048);
        load_lds16(Wg + (size_t)(bn + r0) * ldw + kb + c0 * 8, lB);
        load_lds16(Wg + (size_t)(bn + r1) * ldw + kb + c1 * 8, lB + 2048);
    };

    auto compute = [&](int buf) {
        const unsigned short* Ab_ = As + buf * 4096;
        const unsigned short* Bb_ = Bs + buf * 4096;
        short8 af[4], bv[4];
#pragma unroll
        for (int mi = 0; mi < 4; ++mi)
            af[mi] = *reinterpret_cast<const short8*>(Ab_ + (wr * 64 + mi * 16 + fr) * 32 + cswz * 8);
#pragma unroll
        for (int ni = 0; ni < 4; ++ni)
            bv[ni] = *reinterpret_cast<const short8*>(Bb_ + (wc * 64 + ni * 16 + fr) * 32 + cswz * 8);
#pragma unroll
        for (int mi = 0; mi < 4; ++mi)
#pragma unroll
            for (int ni = 0; ni < 4; ++ni)
                acc[mi][ni] = mfma16(af[mi], bv[ni], acc[mi][ni]);
    };

    // prologue: tiles 0 and 1 in flight (8 outstanding per wave)
    stage(0, 0);
    stage(1, 1);
    asm volatile("s_waitcnt vmcnt(4)" ::: "memory");   // tile 0 landed
    __builtin_amdgcn_s_barrier();

    for (int i = 0; i < nt; ++i) {
        compute(i & 1);
        if (i + 1 < nt) {
            asm volatile("" ::: "memory");             // reads stay before barrier
            __builtin_amdgcn_s_barrier();              // all waves done reading buf
            if (i + 2 < nt) {
                stage(i + 2, i & 1);                   // refill freed buffer
                asm volatile("s_waitcnt vmcnt(4)" ::: "memory");  // tile i+1 landed
            } else {
                asm volatile("s_waitcnt vmcnt(0)" ::: "memory");  // last tile
            }
            __builtin_amdgcn_s_barrier();
        }
    }
}

// GEMM + bias + activation -> bf16 output. ACT: 0 none, 1 lrelu, 2 softplus(lrelu)
template <int ACT>
__global__ __launch_bounds__(256) void k_gemm_act(
    const unsigned short* __restrict__ A1, int lda1, int K1,
    const unsigned short* __restrict__ A2, int lda2, int K2,
    const unsigned short* __restrict__ W1, int ldw1,
    const unsigned short* __restrict__ W2, int ldw2,
    const float* __restrict__ bias,
    unsigned short* __restrict__ DB, int lddb)
{
    __shared__ unsigned short As[8192];
    __shared__ unsigned short Bs[8192];
    const int bm = blockIdx.y * 128, bn = blockIdx.x * 128;
    f32x4 acc[4][4] = {};
    gemm_core(A1, lda1, K1, A2, lda2, K2, W1, ldw1, W2, ldw2, bm, bn, As, Bs, acc);

    const int tid = threadIdx.x, lane = tid & 63, wave = tid >> 6;
    const int wr = wave >> 1, wc = wave & 1, fr = lane & 15, rg = lane >> 4;
    float bb[4];
#pragma unroll
    for (int ni = 0; ni < 4; ++ni)
        bb[ni] = bias ? bias[bn + wc * 64 + ni * 16 + fr] : 0.f;
#pragma unroll
    for (int mi = 0; mi < 4; ++mi)
#pragma unroll
        for (int r = 0; r < 4; ++r) {
            const int row = bm + wr * 64 + mi * 16 + rg * 4 + r;
#pragma unroll
            for (int ni = 0; ni < 4; ++ni) {
                float v = acc[mi][ni][r] + bb[ni];
                if (ACT == 1) v = lrelu_f(v);
                else if (ACT == 2) v = softplus_f(lrelu_f(v));
                DB[(size_t)row * lddb + (bn + wc * 64 + ni * 16 + fr)] = f2b(v);
            }
        }
}

// mean/logvar fused via block-diagonal weight [256 x 1024]:
// cols 0-127 = mean (lrelu) -> out_z, out_mean (f32) + meanb (bf16)
// cols 128-255 = logvar (lrelu) -> out_lv (f32)
__global__ __launch_bounds__(256) void k_meanlv(
    const unsigned short* __restrict__ A,
    const unsigned short* __restrict__ W,
    const float* __restrict__ bias,
    float* __restrict__ oz, float* __restrict__ om, float* __restrict__ olv,
    unsigned short* __restrict__ meanb)
{
    __shared__ unsigned short As[8192];
    __shared__ unsigned short Bs[8192];
    const int bm = blockIdx.y * 128, bn = blockIdx.x * 128;   // bn in {0,128}
    f32x4 acc[4][4] = {};
    gemm_core(A, 1024, 1024, A, 1024, 0, W, 1024, W, 1024, bm, bn, As, Bs, acc);

    const int tid = threadIdx.x, lane = tid & 63, wave = tid >> 6;
    const int wr = wave >> 1, wc = wave & 1, fr = lane & 15, rg = lane >> 4;
    float bb[4];
#pragma unroll
    for (int ni = 0; ni < 4; ++ni)
        bb[ni] = bias[bn + wc * 64 + ni * 16 + fr];
#pragma unroll
    for (int mi = 0; mi < 4; ++mi)
#pragma unroll
        for (int r = 0; r < 4; ++r) {
            const int row = bm + wr * 64 + mi * 16 + rg * 4 + r;
#pragma unroll
            for (int ni = 0; ni < 4; ++ni) {
                const int col = bn + wc * 64 + ni * 16 + fr;
                float v = lrelu_f(acc[mi][ni][r] + bb[ni]);
                if (bn == 0) {  // mean half
                    const size_t o = (size_t)row * (T_ * ZD) + col;
                    oz[o] = v; om[o] = v;
                    meanb[(size_t)row * ZD + col] = f2b(v);
                } else {        // logvar half
                    olv[(size_t)row * (T_ * ZD) + (col - 128)] = v;
                }
            }
        }
}

// gates GEMM with gate-interleaved weight rows + fused LSTM pointwise.
// Reordered col c <-> (group=c>>6, gate=(c>>4)&3, nn=c&15), unit n=group*16+nn.
// h fp32 buffer eliminated: hn written to ohl[t] and oh[t+1] (out_hout[t]==out_hlo[t-1]).
__global__ __launch_bounds__(256) void k_gates_lstm(
    const unsigned short* __restrict__ phib,
    const unsigned short* __restrict__ hbin,
    const unsigned short* __restrict__ Wih,   // [2048][1024] reordered rows
    const unsigned short* __restrict__ Whh,   // [2048][512] reordered rows
    const float* __restrict__ br,             // reordered b_ih+b_hh
    float* __restrict__ c,
    unsigned short* __restrict__ hbout,
    float* __restrict__ ohl,                  // out_hlo + t*HD
    float* __restrict__ oh_next)              // out_hout + (t+1)*HD, or null
{
    __shared__ unsigned short As[8192];
    __shared__ unsigned short Bs[8192];
    const int bm = blockIdx.y * 128, bn = blockIdx.x * 128;
    f32x4 acc[4][4] = {};
    gemm_core(phib, 1024, 1024, hbin, 512, 512, Wih, 1024, Whh, 512, bm, bn, As, Bs, acc);

    const int tid = threadIdx.x, lane = tid & 63, wave = tid >> 6;
    const int wr = wave >> 1, wc = wave & 1, fr = lane & 15, rg = lane >> 4;
    const int n = ((bn + wc * 64) >> 6) * 16 + fr;     // hidden unit index
    float bb[4];
#pragma unroll
    for (int ni = 0; ni < 4; ++ni)
        bb[ni] = br[bn + wc * 64 + ni * 16 + fr];
#pragma unroll
    for (int mi = 0; mi < 4; ++mi)
#pragma unroll
        for (int r = 0; r < 4; ++r) {
            const int row = bm + wr * 64 + mi * 16 + rg * 4 + r;
            const size_t idx = (size_t)row * HD + n;
            const float gi = acc[mi][0][r] + bb[0];
            const float gf = acc[mi][1][r] + bb[1];
            const float gg = acc[mi][2][r] + bb[2];
            const float go = acc[mi][3][r] + bb[3];
            const float co = c[idx];
            const float cn = sigmoid_f(gf) * co + sigmoid_f(gi) * tanhf(gg);
            const float hn = sigmoid_f(go) * tanhf(cn);
            c[idx] = cn;
            hbout[idx] = f2b(hn);
            const size_t ob = (size_t)row * (T_ * HD) + n;
            ohl[ob] = hn;                       // h after update
            if (oh_next) oh_next[ob] = hn;      // == h BEFORE update at t+1
        }
}

// ---------------------------------------------------------------------------
// init: c = 0, hb0 = 0, out_hout[:, 0, :] = 0 (d_out is poisoned by harness)
__global__ __launch_bounds__(256) void init_state(
    float* __restrict__ c, unsigned short* __restrict__ hb,
    float* __restrict__ oh0)
{
    const int i = blockIdx.x * 256 + threadIdx.x;   // B_*HD
    c[i] = 0.f; hb[i] = 0;
    const int b = i >> 9, nn = i & 511;
    oh0[(size_t)b * (T_ * HD) + nn] = 0.f;
}

__global__ __launch_bounds__(256) void f32_to_bf16(
    const float* __restrict__ src, unsigned short* __restrict__ dst, int n4)
{
    const int i = blockIdx.x * 256 + threadIdx.x;
    if (i >= n4) return;
    float4 v = reinterpret_cast<const float4*>(src)[i];
    ushort4 o;
    o.x = f2b(v.x); o.y = f2b(v.y); o.z = f2b(v.z); o.w = f2b(v.w);
    reinterpret_cast<ushort4*>(dst)[i] = o;
}

// all x slices: x [B][T][XD] fp32 -> xball [T][B][XD] bf16.
// One wave handles one (b,t) row: read 256 fp32 linear, write 512 B linear.
__global__ __launch_bounds__(256) void conv_x_all(
    const float* __restrict__ x, unsigned short* __restrict__ xball)
{
    const int i = blockIdx.x * 256 + threadIdx.x;   // < B_*T_*XD/4
    const int d = i & 63;                           // float4 within row
    const int bt = i >> 6;
    const int b = bt / T_, t = bt % T_;
    float4 v = reinterpret_cast<const float4*>(x)[i];
    ushort4 o;
    o.x = f2b(v.x); o.y = f2b(v.y); o.z = f2b(v.z); o.w = f2b(v.w);
    reinterpret_cast<ushort4*>(xball)[((size_t)t * B_ + b) * (XD / 4) + d] = o;
}

// Wub[1024][768] = [Wm1; Wv1] (bf16)
__global__ __launch_bounds__(256) void prep_wu(
    const float* __restrict__ Wm1, const float* __restrict__ Wv1,
    unsigned short* __restrict__ Wub)
{
    const int k = blockIdx.x * 256 + threadIdx.x;   // 0..767
    const int nrow = blockIdx.y;                    // 0..1023
    const float v = nrow < 512 ? Wm1[nrow * 768 + k] : Wv1[(nrow - 512) * 768 + k];
    Wub[nrow * 768 + k] = f2b(v);
}

// Wmlv[256][1024] block-diagonal: [Wm2 0; 0 Wv2] (bf16)
__global__ __launch_bounds__(256) void prep_wmlv(
    const float* __restrict__ Wm2, const float* __restrict__ Wv2,
    unsigned short* __restrict__ Wmlv)
{
    const int k = blockIdx.x * 256 + threadIdx.x;   // 0..1023
    const int cc = blockIdx.y;                      // 0..255
    float v = 0.f;
    if (cc < 128) { if (k < 512) v = Wm2[cc * 512 + k]; }
    else          { if (k >= 512) v = Wv2[(cc - 128) * 512 + (k - 512)]; }
    Wmlv[cc * 1024 + k] = f2b(v);
}

// gate-interleaved reorder of W_ih, W_hh
__global__ __launch_bounds__(256) void prep_wg(
    const float* __restrict__ Wih, const float* __restrict__ Whh,
    unsigned short* __restrict__ Wrih, unsigned short* __restrict__ Wrhh)
{
    const int cc = blockIdx.y;                      // 0..2047
    const int gate = (cc >> 4) & 3;
    const int n = ((cc >> 6) << 4) + (cc & 15);
    const int orig = gate * 512 + n;
    const int kk = blockIdx.x * 256 + threadIdx.x;  // 0..1535
    if (kk < 1024) Wrih[(size_t)cc * 1024 + kk] = f2b(Wih[(size_t)orig * 1024 + kk]);
    else           Wrhh[(size_t)cc * 512 + (kk - 1024)] = f2b(Whh[(size_t)orig * 512 + (kk - 1024)]);
}

// At[k][j] = bf16(A[j][k])  (A is [384][384] fp32 row-major)
__global__ __launch_bounds__(256) void prep_at(
    const float* __restrict__ A, unsigned short* __restrict__ At)
{
    const int i = blockIdx.x * 256 + threadIdx.x;   // 384*384
    const int k = i / DD, j = i % DD;
    At[(size_t)k * DD + j] = f2b(A[(size_t)j * DD + k]);
}

__global__ __launch_bounds__(256) void prep_bias(
    const float* __restrict__ bm1, const float* __restrict__ bv1,
    const float* __restrict__ bm2, const float* __restrict__ bv2,
    const float* __restrict__ bih, const float* __restrict__ bhh,
    float* __restrict__ bu, float* __restrict__ bmlv, float* __restrict__ br)
{
    const int i = blockIdx.x * 256 + threadIdx.x;   // 0..4095
    if (i < 1024) {
        bu[i] = i < 512 ? bm1[i] : bv1[i - 512];
    } else if (i < 1280) {
        const int j = i - 1024;
        bmlv[j] = j < 128 ? bm2[j] : bv2[j - 128];
    } else if (i >= 2048) {
        const int cb = i - 2048;
        const int gate = (cb >> 4) & 3;
        const int n = ((cb >> 6) << 4) + (cb & 15);
        const int orig = gate * 512 + n;
        br[cb] = bih[orig] + bhh[orig];
    }
}

extern "C" void kernel_launch(void* const* d_in, const int* in_sizes, int n_in,
                              void* d_out, int out_size, void* d_ws, size_t ws_size,
                              hipStream_t stream)
{
    const float* x    = (const float*)d_in[0];
    const float* A    = (const float*)d_in[3];
    const float* Wm1  = (const float*)d_in[4];
    const float* bm1  = (const float*)d_in[5];
    const float* Wm2  = (const float*)d_in[6];
    const float* bm2  = (const float*)d_in[7];
    const float* Wv1  = (const float*)d_in[8];
    const float* bv1  = (const float*)d_in[9];
    const float* Wv2  = (const float*)d_in[10];
    const float* bv2  = (const float*)d_in[11];
    const float* Wphi = (const float*)d_in[12];
    const float* bphi = (const float*)d_in[13];
    const float* W_ih = (const float*)d_in[14];
    const float* W_hh = (const float*)d_in[15];
    const float* b_ih = (const float*)d_in[16];
    const float* b_hh = (const float*)d_in[17];

    float* out = (float*)d_out;
    float* out_z    = out;
    float* out_mean = out_z + (size_t)B_ * T_ * ZD;
    float* out_lv   = out_mean + (size_t)B_ * T_ * ZD;
    float* out_hout = out_lv + (size_t)B_ * T_ * ZD;
    float* out_hlo  = out_hout + (size_t)B_ * T_ * HD;

    // ---- workspace layout (~86 MB) ----
    char* wp = (char*)d_ws;
    auto alloc_f = [&](size_t n) { float* p = (float*)wp; wp += n * sizeof(float); return p; };
    auto alloc_b = [&](size_t n) { unsigned short* p = (unsigned short*)wp; wp += n * sizeof(unsigned short); return p; };

    float* c = alloc_f((size_t)B_ * HD);
    unsigned short* hb0   = alloc_b((size_t)B_ * HD);
    unsigned short* hb1   = alloc_b((size_t)B_ * HD);
    unsigned short* xball = alloc_b((size_t)T_ * B_ * XD);
    unsigned short* umuvb = alloc_b((size_t)B_ * 1024);
    unsigned short* meanb = alloc_b((size_t)B_ * ZD);
    unsigned short* phib  = alloc_b((size_t)B_ * 1024);

    unsigned short* Wub   = alloc_b((size_t)1024 * 768);
    unsigned short* Wmlvb = alloc_b((size_t)256 * 1024);
    unsigned short* Atb   = alloc_b((size_t)DD * DD);
    unsigned short* Wphib = alloc_b((size_t)1024 * DD);
    unsigned short* Wcb   = alloc_b((size_t)1024 * DD);
    unsigned short* Wrih  = alloc_b((size_t)2048 * 1024);
    unsigned short* Wrhh  = alloc_b((size_t)2048 * 512);

    float* bu   = alloc_f(1024);
    float* bmlv = alloc_f(256);
    float* br   = alloc_f(2048);

    const dim3 blk(256);

    // ---- prep (once per call) ----
    init_state<<<dim3(B_ * HD / 256), blk, 0, stream>>>(c, hb0, out_hout);
    conv_x_all<<<dim3(B_ * T_ * XD / 4 / 256), blk, 0, stream>>>(x, xball);
    prep_wu<<<dim3(3, 1024), blk, 0, stream>>>(Wm1, Wv1, Wub);
    prep_wmlv<<<dim3(4, 256), blk, 0, stream>>>(Wm2, Wv2, Wmlvb);
    prep_wg<<<dim3(6, 2048), blk, 0, stream>>>(W_ih, W_hh, Wrih, Wrhh);
    prep_bias<<<dim3(16), blk, 0, stream>>>(bm1, bv1, bm2, bv2, b_ih, b_hh, bu, bmlv, br);
    prep_at<<<dim3(DD * DD / 256), blk, 0, stream>>>(A, Atb);
    f32_to_bf16<<<dim3(1024 * DD / 4 / 256), blk, 0, stream>>>(Wphi, Wphib, 1024 * DD / 4);
    // Wc = Wphi @ A  ([1024 x 384] bf16): folds the agg GEMM into phi
    k_gemm_act<0><<<dim3(DD / 128, 1024 / 128), blk, 0, stream>>>(
        Wphib, DD, DD, Wphib, DD, 0,
        Atb, DD, Atb, DD,
        nullptr, Wcb, DD);

    for (int t = 0; t < T_; ++t) {
        unsigned short* hbt = (t & 1) ? hb1 : hb0;   // h_t  (read)
        unsigned short* hbn = (t & 1) ? hb0 : hb1;   // h_{t+1} (written by epilogue)
        const unsigned short* xb = xball + (size_t)t * B_ * XD;

        // [u_m | u_v] = lrelu([x_t, h] @ Wub^T + bu)   [B, 1024]
        k_gemm_act<1><<<dim3(8, 32), blk, 0, stream>>>(
            xb, XD, XD, hbt, HD, HD,
            Wub, XD + HD, Wub + XD, XD + HD,
            bu, umuvb, 1024);

        // mean -> out_z/out_mean/meanb ; logvar -> out_lv
        k_meanlv<<<dim3(2, 32), blk, 0, stream>>>(
            umuvb, Wmlvb, bmlv,
            out_z + (size_t)t * ZD, out_mean + (size_t)t * ZD,
            out_lv + (size_t)t * ZD, meanb);

        // phi = softplus(lrelu([x_t, mean] @ Wc^T + bphi))   [B, 1024]
        k_gemm_act<2><<<dim3(8, 32), blk, 0, stream>>>(
            xb, XD, XD, meanb, ZD, ZD,
            Wcb, DD, Wcb + XD, DD,
            bphi, phib, 1024);

        // gates (reordered) + fused LSTM
        k_gates_lstm<<<dim3(16, 32), blk, 0, stream>>>(
            phib, hbt, Wrih, Wrhh, br,
            c, hbn,
            out_hlo + (size_t)t * HD,
            (t + 1 < T_) ? out_hout + (size_t)(t + 1) * HD : nullptr);
    }
}